// Round 3
// baseline (136.879 us; speedup 1.0000x reference)
//
#include <hip/hip_runtime.h>
#include <hip/hip_bf16.h>

// Problem constants (from reference setup_inputs)
#define BATCH   16
#define C_IN    64
#define LSEQ    4096
#define D_MODEL 256
#define NSTATE  64
#define K_OUT   10
#define NROWS   (BATCH * C_IN)   // 1024 reduce blocks

// ---------------------------------------------------------------------------
// Kernel 1: per-timestep scalar weights, one thread per s (32 blocks x 128).
//   c_k = C^T A^k B (A diagonal) ;  S_m = sum_i C_i B_i (1-a_i^{m+1})/(1-a_i)
//   w_s = S_{L-1-s} / L
// Also zero-inits the completion counter used by the fused kernel (d_ws is
// re-poisoned to 0xAA before every timed call, so this must run every call).
// ---------------------------------------------------------------------------
__global__ void __launch_bounds__(128) k_weights(const float* __restrict__ A,
                                                 const float* __restrict__ Bv,
                                                 const float* __restrict__ Cv,
                                                 float* __restrict__ w,
                                                 unsigned* __restrict__ cnt) {
    if (blockIdx.x == 0 && threadIdx.x == 0) *cnt = 0u;

    __shared__ float l2a[NSTATE];   // log2(a_i)
    __shared__ float inv1[NSTATE];  // 1/(1-a_i)
    __shared__ float cb[NSTATE];    // C_i * B_i
    __shared__ float ash[NSTATE];   // a_i (a==1 guard)

    int tid = threadIdx.x;
    if (tid < NSTATE) {
        float a = A[tid * NSTATE + tid];   // diagonal entry
        ash[tid]  = a;
        cb[tid]   = Cv[tid] * Bv[tid];
        l2a[tid]  = log2f(a);              // a==0 -> -inf: exp2f(-inf)=0, correct
        float d   = 1.0f - a;
        inv1[tid] = (fabsf(d) > 1e-12f) ? (1.0f / d) : 0.0f;
    }
    __syncthreads();

    int s = blockIdx.x * 128 + tid;        // grid covers exactly LSEQ
    float p = (float)(LSEQ - s);           // exponent m+1 = L - s
    float acc = 0.0f;
    #pragma unroll
    for (int i = 0; i < NSTATE; ++i) {
        float g = (ash[i] > 0.99999994f) ? p
                : (1.0f - exp2f(p * l2a[i])) * inv1[i];
        acc = fmaf(cb[i], g, acc);
    }
    w[s] = acc * (1.0f / (float)LSEQ);
}

// ---------------------------------------------------------------------------
// Kernel 2 (fused): per-row weighted reduction over u, then the LAST block to
// finish performs the tiny MLP fold (z = W_up.r + b_up*wsum; out = W_down.z).
// Last-block-done: release fence + device-scope atomicAdd; the block that sees
// old == NROWS-1 acquires and reads everyone's r. No spinning -> graph-safe.
// ---------------------------------------------------------------------------
__global__ void __launch_bounds__(256) k_fused(const float* __restrict__ u,
                                               const float* __restrict__ w,
                                               const float* __restrict__ W_up,
                                               const float* __restrict__ b_up,
                                               const float* __restrict__ W_down,
                                               const float* __restrict__ b_down,
                                               float* __restrict__ r,
                                               unsigned* __restrict__ cnt,
                                               float* __restrict__ out) {
    const int tid  = threadIdx.x;
    const int lane = tid & 63, wid = tid >> 6;
    __shared__ float red[4];
    __shared__ bool  isLast;

    // ---- phase 1: r[rc] = sum_s w_s * u[rc, s] ----
    {
        const int rc = blockIdx.x;
        const float4* up = (const float4*)(u + (size_t)rc * LSEQ);
        const float4* wp = (const float4*)w;
        float acc = 0.0f;
        #pragma unroll
        for (int j = tid; j < LSEQ / 4; j += 256) {
            float4 uv = up[j];
            float4 wv = wp[j];
            acc = fmaf(uv.x, wv.x, acc);
            acc = fmaf(uv.y, wv.y, acc);
            acc = fmaf(uv.z, wv.z, acc);
            acc = fmaf(uv.w, wv.w, acc);
        }
        for (int off = 32; off > 0; off >>= 1) acc += __shfl_down(acc, off, 64);
        if (lane == 0) red[wid] = acc;
        __syncthreads();
        if (tid == 0) {
            r[rc] = red[0] + red[1] + red[2] + red[3];
            __threadfence();   // release our r store (device scope)
            unsigned old = __hip_atomic_fetch_add(cnt, 1u, __ATOMIC_ACQ_REL,
                                                  __HIP_MEMORY_SCOPE_AGENT);
            isLast = (old == NROWS - 1);
        }
        __syncthreads();
    }

    if (!isLast) return;
    __threadfence();           // acquire all blocks' r stores

    // ---- phase 2 (one block): fold the tiny GEMMs ----
    __shared__ float r_sh[NROWS];                 // 4 KB
    __shared__ float z_sh[D_MODEL][BATCH + 1];    // padded: conflict-free
    __shared__ float wsum_sh;

    // wsum = sum_s w_s   (w is 16 KB, L2-resident)
    {
        float acc = 0.0f;
        for (int s = tid; s < LSEQ; s += 256) acc += w[s];
        for (int off = 32; off > 0; off >>= 1) acc += __shfl_down(acc, off, 64);
        __syncthreads();       // red[] reuse hazard
        if (lane == 0) red[wid] = acc;
    }
    for (int e = tid; e < NROWS; e += 256) r_sh[e] = r[e];
    __syncthreads();
    if (tid == 0) wsum_sh = red[0] + red[1] + red[2] + red[3];
    __syncthreads();

    // z[d, b] = W_up[d,:].r[b,:] + b_up[d]*wsum   (thread d owns one row)
    {
        const int d = tid;                        // 256 threads == D_MODEL
        float wrow[C_IN];
        const float4* Wp = (const float4*)(W_up + (size_t)d * C_IN);
        #pragma unroll
        for (int j = 0; j < C_IN / 4; ++j) {
            float4 v = Wp[j];
            wrow[4*j+0] = v.x; wrow[4*j+1] = v.y;
            wrow[4*j+2] = v.z; wrow[4*j+3] = v.w;
        }
        float bz = b_up[d] * wsum_sh;
        #pragma unroll
        for (int b = 0; b < BATCH; ++b) {
            float zz = bz;
            #pragma unroll
            for (int c = 0; c < C_IN; ++c)
                zz = fmaf(wrow[c], r_sh[b * C_IN + c], zz);  // broadcast read
            z_sh[d][b] = zz;
        }
    }
    __syncthreads();

    // out[b,k] = W_down[k,:].z[:,b] + b_down[k]   (160 threads)
    if (tid < BATCH * K_OUT) {
        int b = tid / K_OUT, k = tid % K_OUT;
        float o = b_down[k];
        #pragma unroll 4
        for (int d = 0; d < D_MODEL; ++d)
            o = fmaf(W_down[k * D_MODEL + d], z_sh[d][b], o);
        out[b * K_OUT + k] = o;
    }
}

// ---------------------------------------------------------------------------
extern "C" void kernel_launch(void* const* d_in, const int* in_sizes, int n_in,
                              void* d_out, int out_size, void* d_ws, size_t ws_size,
                              hipStream_t stream) {
    const float* u      = (const float*)d_in[0];
    const float* W_up   = (const float*)d_in[1];
    const float* b_up   = (const float*)d_in[2];
    const float* A      = (const float*)d_in[3];
    const float* Bv     = (const float*)d_in[4];
    const float* Cv     = (const float*)d_in[5];
    const float* W_down = (const float*)d_in[6];
    const float* b_down = (const float*)d_in[7];
    float* out = (float*)d_out;

    float*    w   = (float*)d_ws;            // LSEQ floats
    float*    r   = w + LSEQ;                // NROWS floats
    unsigned* cnt = (unsigned*)(r + NROWS);  // 1 counter

    k_weights<<<LSEQ / 128, 128, 0, stream>>>(A, Bv, Cv, w, cnt);
    k_fused<<<NROWS, 256, 0, stream>>>(u, w, W_up, b_up, W_down, b_down,
                                       r, cnt, out);
}

// Round 4
// 116.331 us; speedup vs baseline: 1.1766x; 1.1766x over previous
//
#include <hip/hip_runtime.h>
#include <hip/hip_bf16.h>

// Problem constants (from reference setup_inputs)
#define BATCH   16
#define C_IN    64
#define LSEQ    4096
#define D_MODEL 256
#define NSTATE  64
#define K_OUT   10
#define NROWS   (BATCH * C_IN)   // 1024 reduce blocks

// ---------------------------------------------------------------------------
// Kernel 1 (40 blocks x 128):
//   blocks 0..31 : w_s = S_{L-1-s}/L, one thread per s.
//                  S_m = sum_i C_i B_i (1-a_i^{m+1})/(1-a_i)   (A diagonal)
//   blocks 32..39: M[k,c] = sum_d W_down[k,d] W_up[d,c]  (80 entries each)
//   block 39 also: out[b,k] = t[k]*wsum + b_down[k]  (base value; k_reduce
//                  atomicAdds the data term on top).  wsum in closed form:
//                  wsum = (1/L) sum_i cb_i inv1_i (L - a_i (1-a_i^L) inv1_i)
// No cross-block dependencies inside the kernel -> no fences needed.
// ---------------------------------------------------------------------------
__global__ void __launch_bounds__(128) k_weights(const float* __restrict__ A,
                                                 const float* __restrict__ Bv,
                                                 const float* __restrict__ Cv,
                                                 const float* __restrict__ W_up,
                                                 const float* __restrict__ b_up,
                                                 const float* __restrict__ W_down,
                                                 const float* __restrict__ b_down,
                                                 float* __restrict__ w,
                                                 float* __restrict__ M,
                                                 float* __restrict__ out) {
    const int tid = threadIdx.x;
    const int blk = blockIdx.x;

    if (blk < 32) {
        // ---------------- w computation ----------------
        __shared__ float l2a[NSTATE];
        __shared__ float inv1[NSTATE];
        __shared__ float cb[NSTATE];
        __shared__ float ash[NSTATE];
        if (tid < NSTATE) {
            float a = A[tid * NSTATE + tid];
            ash[tid]  = a;
            cb[tid]   = Cv[tid] * Bv[tid];
            l2a[tid]  = log2f(a);            // a==0 -> -inf; exp2f(-inf)=0 ok
            float d   = 1.0f - a;
            inv1[tid] = (fabsf(d) > 1e-12f) ? (1.0f / d) : 0.0f;
        }
        __syncthreads();

        int s = blk * 128 + tid;             // covers exactly LSEQ
        float p = (float)(LSEQ - s);         // exponent m+1 = L - s
        float acc = 0.0f;
        #pragma unroll
        for (int i = 0; i < NSTATE; ++i) {
            float g = (ash[i] > 0.99999994f) ? p
                    : (1.0f - exp2f(p * l2a[i])) * inv1[i];
            acc = fmaf(cb[i], g, acc);
        }
        w[s] = acc * (1.0f / (float)LSEQ);
    } else {
        // ---------------- M entries ----------------
        int e = (blk - 32) * 80 + tid;       // 8 blocks x 80 = 640 entries
        if (tid < 80) {
            int k = e >> 6, c = e & 63;
            float m = 0.0f;
            #pragma unroll 4
            for (int d = 0; d < D_MODEL; ++d)
                m = fmaf(W_down[k * D_MODEL + d], W_up[d * C_IN + c], m);
            M[e] = m;
        }
        if (blk == 39) {
            // ---------------- constant output term ----------------
            __shared__ float tsh[K_OUT];
            __shared__ float wsum_sh;
            if (tid >= 80 && tid < 80 + K_OUT) {
                int k = tid - 80;
                float t = 0.0f;
                #pragma unroll 4
                for (int d = 0; d < D_MODEL; ++d)
                    t = fmaf(W_down[k * D_MODEL + d], b_up[d], t);
                tsh[k] = t;
            }
            if (tid == 90) {
                float ws_ = 0.0f;
                for (int i = 0; i < NSTATE; ++i) {
                    float a  = A[i * NSTATE + i];
                    float cb = Cv[i] * Bv[i];
                    float gtot;
                    if (a > 0.99999994f) {
                        gtot = 0.5f * (float)LSEQ * (float)(LSEQ + 1);
                    } else {
                        float inv1 = 1.0f / (1.0f - a);
                        float aL   = exp2f((float)LSEQ * log2f(a)); // a^L
                        gtot = inv1 * ((float)LSEQ - a * (1.0f - aL) * inv1);
                    }
                    ws_ = fmaf(cb, gtot, ws_);
                }
                wsum_sh = ws_ * (1.0f / (float)LSEQ);
            }
            __syncthreads();
            for (int o = tid; o < BATCH * K_OUT; o += 128) {
                int k = o % K_OUT;
                out[o] = fmaf(tsh[k], wsum_sh, b_down[k]);
            }
        }
    }
}

// ---------------------------------------------------------------------------
// Kernel 2: one block per (b,c) row. rv = sum_s w_s * u[b,c,s], then deposit
// the block's own contribution M[k,c]*rv into out[b,k] with 10 relaxed
// device-scope atomicAdds. No fences, no cross-block reads.
// ---------------------------------------------------------------------------
__global__ void __launch_bounds__(256) k_reduce(const float* __restrict__ u,
                                                const float* __restrict__ w,
                                                const float* __restrict__ M,
                                                float* __restrict__ out) {
    const int tid  = threadIdx.x;
    const int lane = tid & 63, wid = tid >> 6;
    const int rc   = blockIdx.x;

    const float4* up = (const float4*)(u + (size_t)rc * LSEQ);
    const float4* wp = (const float4*)w;

    float acc = 0.0f;
    #pragma unroll
    for (int j = tid; j < LSEQ / 4; j += 256) {
        float4 uv = up[j];
        float4 wv = wp[j];
        acc = fmaf(uv.x, wv.x, acc);
        acc = fmaf(uv.y, wv.y, acc);
        acc = fmaf(uv.z, wv.z, acc);
        acc = fmaf(uv.w, wv.w, acc);
    }
    for (int off = 32; off > 0; off >>= 1) acc += __shfl_down(acc, off, 64);

    __shared__ float red[4];
    __shared__ float rv;
    if (lane == 0) red[wid] = acc;
    __syncthreads();
    if (tid == 0) rv = red[0] + red[1] + red[2] + red[3];
    __syncthreads();

    if (tid < K_OUT) {
        int b = rc >> 6, c = rc & 63;
        atomicAdd(out + b * K_OUT + tid, M[tid * C_IN + c] * rv);
    }
}

// ---------------------------------------------------------------------------
extern "C" void kernel_launch(void* const* d_in, const int* in_sizes, int n_in,
                              void* d_out, int out_size, void* d_ws, size_t ws_size,
                              hipStream_t stream) {
    const float* u      = (const float*)d_in[0];
    const float* W_up   = (const float*)d_in[1];
    const float* b_up   = (const float*)d_in[2];
    const float* A      = (const float*)d_in[3];
    const float* Bv     = (const float*)d_in[4];
    const float* Cv     = (const float*)d_in[5];
    const float* W_down = (const float*)d_in[6];
    const float* b_down = (const float*)d_in[7];
    float* out = (float*)d_out;

    float* w = (float*)d_ws;        // LSEQ floats
    float* M = w + LSEQ;            // K_OUT*C_IN floats

    k_weights<<<40, 128, 0, stream>>>(A, Bv, Cv, W_up, b_up, W_down, b_down,
                                      w, M, out);
    k_reduce<<<NROWS, 256, 0, stream>>>(u, w, M, out);
}

// Round 5
// 97.963 us; speedup vs baseline: 1.3973x; 1.1875x over previous
//
#include <hip/hip_runtime.h>
#include <hip/hip_bf16.h>

// Problem constants (from reference setup_inputs)
#define BATCH   16
#define C_IN    64
#define LSEQ    4096
#define D_MODEL 256
#define NSTATE  64
#define K_OUT   10
#define NROWS   (BATCH * C_IN)   // 1024 reduce blocks

// ---------------------------------------------------------------------------
// Kernel 1 (41 blocks x 128):
//   blocks 0..31 : w_s = S_{L-1-s}/L, one thread per s.
//                  S_m = sum_i C_i B_i (1-a_i^{m+1})/(1-a_i)   (A diagonal)
//   blocks 32..39: M[k,c] = sum_d W_down[k,d] W_up[d,c]  (80 entries each)
//   block 40     : out[b,k] = t[k]*wsum + b_down[k]  (base; k_reduce atomics
//                  add the data term). All parallel — no serial lanes:
//                  wsum: thread i owns state i, wave-reduce.
//                  t[k]: 8 threads per k, segment shuffle-reduce (width=8).
// ---------------------------------------------------------------------------
__global__ void __launch_bounds__(128) k_weights(const float* __restrict__ A,
                                                 const float* __restrict__ Bv,
                                                 const float* __restrict__ Cv,
                                                 const float* __restrict__ W_up,
                                                 const float* __restrict__ b_up,
                                                 const float* __restrict__ W_down,
                                                 const float* __restrict__ b_down,
                                                 float* __restrict__ w,
                                                 float* __restrict__ M,
                                                 float* __restrict__ out) {
    const int tid = threadIdx.x;
    const int blk = blockIdx.x;

    if (blk < 32) {
        // ---------------- w computation ----------------
        __shared__ float l2a[NSTATE];
        __shared__ float inv1[NSTATE];
        __shared__ float cb[NSTATE];
        __shared__ float ash[NSTATE];
        if (tid < NSTATE) {
            float a = A[tid * NSTATE + tid];
            ash[tid]  = a;
            cb[tid]   = Cv[tid] * Bv[tid];
            l2a[tid]  = log2f(a);            // a==0 -> -inf; exp2f(-inf)=0 ok
            float d   = 1.0f - a;
            inv1[tid] = (fabsf(d) > 1e-12f) ? (1.0f / d) : 0.0f;
        }
        __syncthreads();

        int s = blk * 128 + tid;             // covers exactly LSEQ
        float p = (float)(LSEQ - s);         // exponent m+1 = L - s
        float acc = 0.0f;
        #pragma unroll
        for (int i = 0; i < NSTATE; ++i) {
            float g = (ash[i] > 0.99999994f) ? p
                    : (1.0f - exp2f(p * l2a[i])) * inv1[i];
            acc = fmaf(cb[i], g, acc);
        }
        w[s] = acc * (1.0f / (float)LSEQ);
    } else if (blk < 40) {
        // ---------------- M entries (80 per block) ----------------
        int e = (blk - 32) * 80 + tid;       // 8 blocks x 80 = 640 entries
        if (tid < 80) {
            int k = e >> 6, c = e & 63;
            float m = 0.0f;
            #pragma unroll 4
            for (int d = 0; d < D_MODEL; ++d)
                m = fmaf(W_down[k * D_MODEL + d], W_up[d * C_IN + c], m);
            M[e] = m;
        }
    } else {
        // ---------------- constant output term (all-parallel) ----------------
        __shared__ float tsh[K_OUT];
        __shared__ float wsum_sh;

        // wsum: one state per thread (tid<64 = wave 0), closed form:
        //   wsum = (1/L) sum_i cb_i inv1_i (L - a_i (1-a_i^L) inv1_i)
        float ws_part = 0.0f;
        if (tid < NSTATE) {
            float a   = A[tid * NSTATE + tid];
            float cbv = Cv[tid] * Bv[tid];
            float gtot;
            if (a > 0.99999994f) {
                gtot = 0.5f * (float)LSEQ * (float)(LSEQ + 1);
            } else {
                float inv1 = 1.0f / (1.0f - a);
                float aL   = exp2f((float)LSEQ * log2f(a));   // a^L
                gtot = inv1 * ((float)LSEQ - a * (1.0f - aL) * inv1);
            }
            ws_part = cbv * gtot;
        }
        if (tid < 64) {
            for (int off = 32; off > 0; off >>= 1)
                ws_part += __shfl_down(ws_part, off, 64);
            if (tid == 0) wsum_sh = ws_part * (1.0f / (float)LSEQ);
        }

        // t[k] = W_down[k,:].b_up : 8 threads per k (tid<80), coalesced-ish
        if (tid < 8 * K_OUT) {
            int k = tid >> 3, j = tid & 7;
            float t = 0.0f;
            for (int d = j; d < D_MODEL; d += 8)
                t = fmaf(W_down[k * D_MODEL + d], b_up[d], t);
            for (int off = 4; off > 0; off >>= 1)
                t += __shfl_down(t, off, 8);             // 8-lane segments
            if (j == 0) tsh[k] = t;
        }
        __syncthreads();

        for (int o = tid; o < BATCH * K_OUT; o += 128) {
            int k = o % K_OUT;
            out[o] = fmaf(tsh[k], wsum_sh, b_down[k]);
        }
    }
}

// ---------------------------------------------------------------------------
// Kernel 2: one block per (b,c) row. rv = sum_s w_s * u[b,c,s], then deposit
// the block's own contribution M[k,c]*rv into out[b,k] with 10 relaxed
// device-scope atomicAdds. No fences, no cross-block reads.
// ---------------------------------------------------------------------------
__global__ void __launch_bounds__(256) k_reduce(const float* __restrict__ u,
                                                const float* __restrict__ w,
                                                const float* __restrict__ M,
                                                float* __restrict__ out) {
    const int tid  = threadIdx.x;
    const int lane = tid & 63, wid = tid >> 6;
    const int rc   = blockIdx.x;

    const float4* up = (const float4*)(u + (size_t)rc * LSEQ);
    const float4* wp = (const float4*)w;

    float acc = 0.0f;
    #pragma unroll
    for (int j = tid; j < LSEQ / 4; j += 256) {
        float4 uv = up[j];
        float4 wv = wp[j];
        acc = fmaf(uv.x, wv.x, acc);
        acc = fmaf(uv.y, wv.y, acc);
        acc = fmaf(uv.z, wv.z, acc);
        acc = fmaf(uv.w, wv.w, acc);
    }
    for (int off = 32; off > 0; off >>= 1) acc += __shfl_down(acc, off, 64);

    __shared__ float red[4];
    __shared__ float rv;
    if (lane == 0) red[wid] = acc;
    __syncthreads();
    if (tid == 0) rv = red[0] + red[1] + red[2] + red[3];
    __syncthreads();

    if (tid < K_OUT) {
        int b = rc >> 6, c = rc & 63;
        atomicAdd(out + b * K_OUT + tid, M[tid * C_IN + c] * rv);
    }
}

// ---------------------------------------------------------------------------
extern "C" void kernel_launch(void* const* d_in, const int* in_sizes, int n_in,
                              void* d_out, int out_size, void* d_ws, size_t ws_size,
                              hipStream_t stream) {
    const float* u      = (const float*)d_in[0];
    const float* W_up   = (const float*)d_in[1];
    const float* b_up   = (const float*)d_in[2];
    const float* A      = (const float*)d_in[3];
    const float* Bv     = (const float*)d_in[4];
    const float* Cv     = (const float*)d_in[5];
    const float* W_down = (const float*)d_in[6];
    const float* b_down = (const float*)d_in[7];
    float* out = (float*)d_out;

    float* w = (float*)d_ws;        // LSEQ floats
    float* M = w + LSEQ;            // K_OUT*C_IN floats

    k_weights<<<41, 128, 0, stream>>>(A, Bv, Cv, W_up, b_up, W_down, b_down,
                                      w, M, out);
    k_reduce<<<NROWS, 256, 0, stream>>>(u, w, M, out);
}